// Round 5
// baseline (330.779 us; speedup 1.0000x reference)
//
#include <hip/hip_runtime.h>

// relative_depth_crit — R8: bucketed tile-sweep + counted-vmcnt pipeline.
// R7b post-mortem: bucketing worked (probe VALU gone, exact answer) but dur
// stuck at 158us = 64 iters x ~2.9K cyc: each __syncthreads() forces
// vmcnt(0), draining the stage(t+1) DMA issued only ~300cy earlier -> every
// tile pays full L2/HBM latency + barrier skew. Fix = T4 (counted vmcnt,
// never 0 in-loop) + raw s_barrier + depth-3 buffering:
//   TE=4096 (bin=key>>12), T=80, 3 buffers, 16 loads/tile = 2/wave (uniform
//   -> countable). Per iter: s_waitcnt vmcnt(2) [stage(t+1) stays in flight]
//   -> s_barrier -> issue stage(t+2) -> resolve tile t. Stage(t) gets two
//   whole iterations of slack instead of ~300cy.
// Hazards: buffer reuse fenced by the barrier BEFORE the stage issue; no
// other global ops in-loop so vmcnt counts exactly stage loads; tile
// ds_reads are value-consumed before the barrier so no lgkm drain needed;
// asm "memory" clobber + sched_barrier(0) pin compiler motion (rule #18).

constexpr int B = 64;
constexpr int H = 512;
constexpr int W = 640;
constexpr int P = 100000;
constexpr int HWSZ = H * W;            // 327680 floats = 1.31 MB per batch
constexpr int N4B = P / 4;             // 25000 vec4 per batch
constexpr int NCHUNK = 8;              // blocks per batch
constexpr int C4 = N4B / NCHUNK;       // 3125 vec4 per block
constexpr int THREADS = 512;           // 8 waves
constexpr int NWAVE = 8;
constexpr int SLOTS = 7;               // ceil(3125/512) vec4 per thread
constexpr int NG = SLOTS * 8;          // 56 endpoints per thread
constexpr int NE = C4 * 8;             // 25000 endpoints per block (exact)
constexpr int TE = 4096;               // tile elems (16 KB); bin = key>>12
constexpr int T = HWSZ / TE;           // 80 tiles
constexpr int NBUF = 3;                // depth-3 rolling buffers
constexpr int NBLK = B * NCHUNK;       // 512
constexpr float INV_N = 1.0f / (float)(B * P);
constexpr float MARGIN = 1.0f;

typedef int vint4 __attribute__((ext_vector_type(4)));

__device__ __forceinline__ float loss_from(float za, float zb, int od) {
    float zd = za - zb;
    float gt = (float)(od - 1);           // {-1, 0, 1}
    float mask = fabsf(gt);               // {0, 1}
    float t = fminf(gt * zd, MARGIN);
    float l_rank = __logf(1.0f + __expf(-t));
    float l_eq = fmaxf(zd * zd, MARGIN * MARGIN);
    return mask * l_rank + (1.0f - mask) * l_eq;
}

// Stage one 16 KB tile: 16 wave-loads of 1 KB, exactly 2 per wave (uniform
// count -> per-wave vmcnt arithmetic is exact). LDS dest wave-uniform base.
__device__ __forceinline__ void stage_tile(const float* __restrict__ src,
                                           float* dst, int wid, int lane) {
    #pragma unroll
    for (int r = 0; r < 2; ++r) {
        int cb = (wid * 2 + r) * 256;     // float offset of this 1 KB chunk
        __builtin_amdgcn_global_load_lds(
            (const __attribute__((address_space(1))) void*)(src + cb + lane * 4),
            (__attribute__((address_space(3))) void*)(dst + cb),
            16, 0, 0);
    }
}

__global__ __launch_bounds__(THREADS) void rdc_sweep(
        const float* __restrict__ depth,
        const vint4* __restrict__ xA, const vint4* __restrict__ yA,
        const vint4* __restrict__ xB, const vint4* __restrict__ yB,
        const vint4* __restrict__ ord,
        float* __restrict__ partials) {
    __shared__ unsigned cells[NE];        // 100000 B: entry rel, then z bits
    __shared__ float tiles[NBUF][TE];     //  49152 B, triple-buffered
    __shared__ unsigned hist[NWAVE][T];   //   2560 B: per-wave histograms
    __shared__ unsigned cur[NWAVE][T];    //   2560 B: per-(wave,bin) cursors
    __shared__ unsigned startB[T + 1];    //    324 B: bin starts (excl scan)
    __shared__ float wsum[NWAVE];         // total ~154.6 KB -> 1 block/CU

    // XCD pinning: j%8 ~ XCD; batch b lives on XCD b&7; its 8 chunks co-sweep
    // tiles and share the image in that XCD's L2 (1.31 MB < 4 MB).
    const int j = blockIdx.x;
    const int x = j & 7;
    const int g = j >> 3;                 // 0..63
    const int chunk = g & 7;
    const int b = ((g >> 3) << 3) + x;    // 0..63, on XCD b&7

    const int tid = threadIdx.x;
    const int lane = tid & 63;
    const int wid = tid >> 6;

    const float* dimg = depth + (size_t)b * HWSZ;

    // prologue: tile 0 DMA streams under the index/bucketing phases
    stage_tile(dimg, &tiles[0][0], wid, lane);

    // zero replica histograms (cur fully overwritten by the scan wave):
    // 8*80 = 640 words
    ((unsigned*)hist)[tid] = 0u;
    if (tid < NWAVE * T - THREADS) ((unsigned*)hist)[THREADS + tid] = 0u;

    // ---- index phase: 56 register-held keys + packed ordinals ----
    const int base4 = b * N4B + chunk * C4;
    const bool v6 = (tid < C4 - (SLOTS - 1) * THREADS);   // slot-6 validity (tid<53)
    unsigned key[NG];                     // becomes cell-index array after placement
    int pack[SLOTS];
    #pragma unroll
    for (int i = 0; i < SLOTS; ++i) {
        int c = i * THREADS + tid;
        if (c > C4 - 1) c = C4 - 1;       // clamp tail (i==6, tid>=53)
        int idx = base4 + c;
        vint4 xa = __builtin_nontemporal_load(&xA[idx]);
        vint4 ya = __builtin_nontemporal_load(&yA[idx]);
        vint4 xb = __builtin_nontemporal_load(&xB[idx]);
        vint4 yb = __builtin_nontemporal_load(&yB[idx]);
        vint4 od = __builtin_nontemporal_load(&ord[idx]);
        key[i*8+0] = ya.x * W + xa.x;  key[i*8+1] = yb.x * W + xb.x;
        key[i*8+2] = ya.y * W + xa.y;  key[i*8+3] = yb.y * W + xb.y;
        key[i*8+4] = ya.z * W + xa.z;  key[i*8+5] = yb.z * W + xb.z;
        key[i*8+6] = ya.w * W + xa.w;  key[i*8+7] = yb.w * W + xb.w;
        pack[i] = (od.x & 3) | ((od.y & 3) << 2) | ((od.z & 3) << 4)
                | ((od.w & 3) << 6);
    }
    __syncthreads();                      // hist zeroed

    // ---- histogram: per-wave replica rows kill cross-wave contention ----
    #pragma unroll
    for (int k = 0; k < NG; ++k) {
        if (k < 48 || v6) {               // skip clamped duplicates entirely
            unsigned bin = key[k] >> 12;  // TE = 4096
            atomicAdd(&hist[wid][bin], 1u);
        }
    }
    __syncthreads();

    // ---- prefix scan (wave 0): lane l < 40 owns bins 2l, 2l+1 ----
    if (wid == 0) {
        unsigned h0[NWAVE], h1[NWAVE];
        unsigned sum0 = 0, sum1 = 0;
        const int b0 = 2 * lane, b1 = 2 * lane + 1;
        if (lane < T / 2) {
            #pragma unroll
            for (int w = 0; w < NWAVE; ++w) h0[w] = hist[w][b0];
            #pragma unroll
            for (int w = 0; w < NWAVE; ++w) h1[w] = hist[w][b1];
            #pragma unroll
            for (int w = 0; w < NWAVE; ++w) { unsigned t_ = h0[w]; h0[w] = sum0; sum0 += t_; }
            #pragma unroll
            for (int w = 0; w < NWAVE; ++w) { unsigned t_ = h1[w]; h1[w] = sum1; sum1 += t_; }
        }
        unsigned pair = sum0 + sum1;      // 0 for lane >= 40
        unsigned inc = pair;
        #pragma unroll
        for (int d = 1; d < 64; d <<= 1) {
            unsigned n = __shfl_up(inc, d, 64);
            if (lane >= d) inc += n;
        }
        unsigned ex = inc - pair;         // exclusive over bin-pairs
        if (lane < T / 2) {
            unsigned s0 = ex, s1 = ex + sum0;
            startB[b0] = s0;
            startB[b1] = s1;
            if (lane == T / 2 - 1) startB[T] = s1 + sum1;   // == NE
            #pragma unroll
            for (int w = 0; w < NWAVE; ++w) {
                cur[w][b0] = s0 + h0[w];
                cur[w][b1] = s1 + h1[w];
            }
        }
    }
    __syncthreads();

    // ---- placement: scatter rel-offsets into exact-sized bins ----
    #pragma unroll
    for (int k = 0; k < NG; ++k) {
        if (k < 48 || v6) {
            unsigned kk = key[k];
            unsigned bin = kk >> 12;
            unsigned rel = kk & (unsigned)(TE - 1);
            unsigned pos = atomicAdd(&cur[wid][bin], 1u);
            cells[pos] = rel;
            key[k] = pos;                 // reuse reg: key -> cell index
        } else {
            key[k] = 0u;                  // safe in-bounds readback, weight 0
        }
    }
    __syncthreads();                      // placement visible; drains vmcnt(0)
                                          // (stage(0) landed; counter now 0)
    // prologue part 2: tile 1 in flight (outstanding = 2 at loop entry)
    stage_tile(dimg + TE, &tiles[1][0], wid, lane);

    // ---- pipelined tile sweep: counted vmcnt, raw s_barrier ----
    int r3 = 0;                           // buffer holding tile t
    int s3 = 2;                           // buffer for tile t+2
    #pragma unroll 1
    for (int t = 0; t < T; ++t) {
        // wait own stage(t) (all but the 2 newest = stage(t+1)); last iter
        // has nothing newer in flight -> full drain.
        if (t < T - 1) { asm volatile("s_waitcnt vmcnt(2)" ::: "memory"); }
        else           { asm volatile("s_waitcnt vmcnt(0)" ::: "memory"); }
        __builtin_amdgcn_sched_barrier(0);
        __builtin_amdgcn_s_barrier();     // all waves: stage(t) landed AND
                                          // tile t-1 fully resolved
        __builtin_amdgcn_sched_barrier(0);
        if (t + 2 < T)
            stage_tile(dimg + (t + 2) * TE, &tiles[s3][0], wid, lane);

        const float* tb = &tiles[r3][0];
        unsigned s = startB[t];
        unsigned e = startB[t + 1];
        for (unsigned u = s + tid; u < e; u += THREADS) {
            unsigned rel = cells[u];
            cells[u] = __float_as_uint(tb[rel]);
        }
        r3 = (r3 == NBUF - 1) ? 0 : r3 + 1;
        s3 = (s3 == NBUF - 1) ? 0 : s3 + 1;
        __builtin_amdgcn_sched_barrier(0);
    }
    __syncthreads();                      // all z writes visible

    // ---- readback + loss ----
    float acc = 0.0f;
    #pragma unroll
    for (int i = 0; i < SLOTS; ++i) {
        float li = 0.0f;
        #pragma unroll
        for (int q = 0; q < 4; ++q) {
            float za = __uint_as_float(cells[key[i*8 + 2*q]]);
            float zb = __uint_as_float(cells[key[i*8 + 2*q + 1]]);
            li += loss_from(za, zb, (pack[i] >> (2 * q)) & 3);
        }
        if (i == SLOTS - 1) li *= (v6 ? 1.0f : 0.0f);
        acc += li;
    }

    // ---- wave + block reduction ----
    #pragma unroll
    for (int off2 = 32; off2 > 0; off2 >>= 1)
        acc += __shfl_down(acc, off2, 64);
    if (lane == 0) wsum[wid] = acc;
    __syncthreads();
    if (wid == 0) {
        float v = (lane < NWAVE) ? wsum[lane] : 0.0f;
        #pragma unroll
        for (int off2 = 4; off2 > 0; off2 >>= 1)
            v += __shfl_down(v, off2, 64);
        if (lane == 0) partials[j] = v;
    }
}

__global__ __launch_bounds__(256) void rdc_finalize(
        const float* __restrict__ partials, float* __restrict__ out, int n) {
    float acc = 0.0f;
    for (int k = threadIdx.x; k < n; k += 256)
        acc += partials[k];
    #pragma unroll
    for (int off = 32; off > 0; off >>= 1)
        acc += __shfl_down(acc, off, 64);
    __shared__ float wsum[4];
    int lane = threadIdx.x & 63;
    int wid  = threadIdx.x >> 6;
    if (lane == 0) wsum[wid] = acc;
    __syncthreads();
    if (wid == 0 && lane == 0)
        out[0] = (wsum[0] + wsum[1] + wsum[2] + wsum[3]) * INV_N;
}

extern "C" void kernel_launch(void* const* d_in, const int* in_sizes, int n_in,
                              void* d_out, int out_size, void* d_ws, size_t ws_size,
                              hipStream_t stream) {
    const float* depth = (const float*)d_in[0];
    const vint4* xA = (const vint4*)d_in[1];
    const vint4* yA = (const vint4*)d_in[2];
    const vint4* xB = (const vint4*)d_in[3];
    const vint4* yB = (const vint4*)d_in[4];
    const vint4* ord = (const vint4*)d_in[5];
    float* out = (float*)d_out;

    float* partials = (float*)d_ws;      // NBLK*4 = 2 KB, ws is plenty
    rdc_sweep<<<NBLK, THREADS, 0, stream>>>(depth, xA, yA, xB, yB, ord, partials);
    rdc_finalize<<<1, 256, 0, stream>>>(partials, out, NBLK);
}

// Round 6
// 290.460 us; speedup vs baseline: 1.1388x; 1.1388x over previous
//
#include <hip/hip_runtime.h>

// relative_depth_crit — R9: bucketed tile-sweep, reg-staged tiles.
// R8 post-mortem: per-64B-line staging rate is invariant across tile sizes
// and barrier schemes (R5:0.106, R7b:0.108, R8:0.094 lines/cyc/CU) ->
// global_load_lds from a single block sustains only ~6.8 B/cyc/CU, 9x below
// the ~60 B/cyc/CU L2 rate of VGPR-return vector loads (m56). The DMA engine
// was the wall all along. R9 stages tiles via VGPRs: per tile each thread
// loads 2x dwordx4 (contiguous, L2-cached) one tile ahead, ds_write_b128s
// into the double-buffered tile, one __syncthreads per tile (its vmcnt(0)
// drain is free: ds_write already consumed the loads). Counting-sort
// bucketing (R7) unchanged: O(1) DS ops per endpoint.

constexpr int B = 64;
constexpr int H = 512;
constexpr int W = 640;
constexpr int P = 100000;
constexpr int HWSZ = H * W;            // 327680 floats = 1.31 MB per batch
constexpr int N4B = P / 4;             // 25000 vec4 per batch
constexpr int NCHUNK = 8;              // blocks per batch
constexpr int C4 = N4B / NCHUNK;       // 3125 vec4 per block
constexpr int THREADS = 512;           // 8 waves
constexpr int NWAVE = 8;
constexpr int SLOTS = 7;               // ceil(3125/512) vec4 per thread
constexpr int NG = SLOTS * 8;          // 56 endpoints per thread
constexpr int NE = C4 * 8;             // 25000 endpoints per block (exact)
constexpr int TE = 4096;               // tile elems (16 KB); bin = key>>12
constexpr int T = HWSZ / TE;           // 80 tiles
constexpr int NBLK = B * NCHUNK;       // 512
constexpr float INV_N = 1.0f / (float)(B * P);
constexpr float MARGIN = 1.0f;

typedef int vint4 __attribute__((ext_vector_type(4)));
typedef float vfloat4 __attribute__((ext_vector_type(4)));

__device__ __forceinline__ float loss_from(float za, float zb, int od) {
    float zd = za - zb;
    float gt = (float)(od - 1);           // {-1, 0, 1}
    float mask = fabsf(gt);               // {0, 1}
    float t = fminf(gt * zd, MARGIN);
    float l_rank = __logf(1.0f + __expf(-t));
    float l_eq = fmaxf(zd * zd, MARGIN * MARGIN);
    return mask * l_rank + (1.0f - mask) * l_eq;
}

__global__ __launch_bounds__(THREADS) void rdc_sweep(
        const float* __restrict__ depth,
        const vint4* __restrict__ xA, const vint4* __restrict__ yA,
        const vint4* __restrict__ xB, const vint4* __restrict__ yB,
        const vint4* __restrict__ ord,
        float* __restrict__ partials) {
    __shared__ unsigned cells[NE];        // 100000 B: entry rel, then z bits
    __shared__ float tiles[2][TE];        //  32768 B, double-buffered
    __shared__ unsigned hist[NWAVE][T];   //   2560 B: per-wave histograms
    __shared__ unsigned cur[NWAVE][T];    //   2560 B: per-(wave,bin) cursors
    __shared__ unsigned startB[T + 1];    //    324 B: bin starts (excl scan)
    __shared__ float wsum[NWAVE];         // total ~138.2 KB -> 1 block/CU

    // XCD pinning: j%8 ~ XCD; batch b lives on XCD b&7; its 8 chunks co-sweep
    // tiles and share the image in that XCD's L2 (1.31 MB < 4 MB).
    const int j = blockIdx.x;
    const int x = j & 7;
    const int g = j >> 3;                 // 0..63
    const int chunk = g & 7;
    const int b = ((g >> 3) << 3) + x;    // 0..63, on XCD b&7

    const int tid = threadIdx.x;
    const int lane = tid & 63;
    const int wid = tid >> 6;

    const float* dimg = depth + (size_t)b * HWSZ;

    // prologue: tile 0 -> regs; issued first so it streams under index phase
    const vfloat4* s40 = (const vfloat4*)dimg;
    vfloat4 ld0a = s40[tid];
    vfloat4 ld0b = s40[THREADS + tid];

    // zero replica histograms (cur fully overwritten by the scan wave):
    // 8*80 = 640 words
    ((unsigned*)hist)[tid] = 0u;
    if (tid < NWAVE * T - THREADS) ((unsigned*)hist)[THREADS + tid] = 0u;

    // ---- index phase: 56 register-held keys + packed ordinals ----
    const int base4 = b * N4B + chunk * C4;
    const bool v6 = (tid < C4 - (SLOTS - 1) * THREADS);   // slot-6 validity (tid<53)
    unsigned key[NG];                     // becomes cell-index array after placement
    int pack[SLOTS];
    #pragma unroll
    for (int i = 0; i < SLOTS; ++i) {
        int c = i * THREADS + tid;
        if (c > C4 - 1) c = C4 - 1;       // clamp tail (i==6, tid>=53)
        int idx = base4 + c;
        vint4 xa = __builtin_nontemporal_load(&xA[idx]);
        vint4 ya = __builtin_nontemporal_load(&yA[idx]);
        vint4 xb = __builtin_nontemporal_load(&xB[idx]);
        vint4 yb = __builtin_nontemporal_load(&yB[idx]);
        vint4 od = __builtin_nontemporal_load(&ord[idx]);
        key[i*8+0] = ya.x * W + xa.x;  key[i*8+1] = yb.x * W + xb.x;
        key[i*8+2] = ya.y * W + xa.y;  key[i*8+3] = yb.y * W + xb.y;
        key[i*8+4] = ya.z * W + xa.z;  key[i*8+5] = yb.z * W + xb.z;
        key[i*8+6] = ya.w * W + xa.w;  key[i*8+7] = yb.w * W + xb.w;
        pack[i] = (od.x & 3) | ((od.y & 3) << 2) | ((od.z & 3) << 4)
                | ((od.w & 3) << 6);
    }
    __syncthreads();                      // hist zeroed

    // ---- histogram: per-wave replica rows kill cross-wave contention ----
    #pragma unroll
    for (int k = 0; k < NG; ++k) {
        if (k < 48 || v6) {               // skip clamped duplicates entirely
            unsigned bin = key[k] >> 12;  // TE = 4096
            atomicAdd(&hist[wid][bin], 1u);
        }
    }
    __syncthreads();

    // ---- prefix scan (wave 0): lane l < 40 owns bins 2l, 2l+1 ----
    if (wid == 0) {
        unsigned h0[NWAVE], h1[NWAVE];
        unsigned sum0 = 0, sum1 = 0;
        const int b0 = 2 * lane, b1 = 2 * lane + 1;
        if (lane < T / 2) {
            #pragma unroll
            for (int w = 0; w < NWAVE; ++w) h0[w] = hist[w][b0];
            #pragma unroll
            for (int w = 0; w < NWAVE; ++w) h1[w] = hist[w][b1];
            #pragma unroll
            for (int w = 0; w < NWAVE; ++w) { unsigned t_ = h0[w]; h0[w] = sum0; sum0 += t_; }
            #pragma unroll
            for (int w = 0; w < NWAVE; ++w) { unsigned t_ = h1[w]; h1[w] = sum1; sum1 += t_; }
        }
        unsigned pair = sum0 + sum1;      // 0 for lane >= 40
        unsigned inc = pair;
        #pragma unroll
        for (int d = 1; d < 64; d <<= 1) {
            unsigned n = __shfl_up(inc, d, 64);
            if (lane >= d) inc += n;
        }
        unsigned ex = inc - pair;         // exclusive over bin-pairs
        if (lane < T / 2) {
            unsigned s0 = ex, s1 = ex + sum0;
            startB[b0] = s0;
            startB[b1] = s1;
            if (lane == T / 2 - 1) startB[T] = s1 + sum1;   // == NE
            #pragma unroll
            for (int w = 0; w < NWAVE; ++w) {
                cur[w][b0] = s0 + h0[w];
                cur[w][b1] = s1 + h1[w];
            }
        }
    }
    __syncthreads();

    // ---- placement: scatter rel-offsets into exact-sized bins ----
    #pragma unroll
    for (int k = 0; k < NG; ++k) {
        if (k < 48 || v6) {
            unsigned kk = key[k];
            unsigned bin = kk >> 12;
            unsigned rel = kk & (unsigned)(TE - 1);
            unsigned pos = atomicAdd(&cur[wid][bin], 1u);
            cells[pos] = rel;
            key[k] = pos;                 // reuse reg: key -> cell index
        } else {
            key[k] = 0u;                  // safe in-bounds readback, weight 0
        }
    }

    // prologue part 2: write tile 0 (loads long landed), prefetch tile 1
    vfloat4 r0, r1;
    {
        vfloat4* d4 = (vfloat4*)&tiles[0][0];
        d4[tid] = ld0a;
        d4[THREADS + tid] = ld0b;
        const vfloat4* s4 = (const vfloat4*)(dimg + TE);
        r0 = s4[tid];
        r1 = s4[THREADS + tid];
    }
    __syncthreads();                      // placement + tile0 writes visible

    // ---- reg-staged pipelined tile sweep ----
    // iter t invariant at top: buf[t&1] holds tile t (sealed by barrier);
    // regs hold tile t+1. Body: write t+1 -> buf[(t+1)&1] (that buffer's
    // readers, tile t-1, finished before the last barrier); prefetch t+2;
    // resolve tile t; barrier (seals writes of t+1 + reads of t).
    #pragma unroll 1
    for (int t = 0; t < T; ++t) {
        if (t + 1 < T) {
            vfloat4* d4 = (vfloat4*)&tiles[(t + 1) & 1][0];
            d4[tid] = r0;                 // implicit vmcnt wait on t+1 loads
            d4[THREADS + tid] = r1;
        }
        if (t + 2 < T) {
            const vfloat4* s4 = (const vfloat4*)(dimg + (size_t)(t + 2) * TE);
            r0 = s4[tid];                 // t+2 -> regs, ~1 iter of slack
            r1 = s4[THREADS + tid];
        }
        const float* tb = &tiles[t & 1][0];
        unsigned s = startB[t];
        unsigned e = startB[t + 1];
        for (unsigned u = s + tid; u < e; u += THREADS) {
            unsigned rel = cells[u];
            cells[u] = __float_as_uint(tb[rel]);
        }
        __syncthreads();
    }

    // ---- readback + loss ----
    float acc = 0.0f;
    #pragma unroll
    for (int i = 0; i < SLOTS; ++i) {
        float li = 0.0f;
        #pragma unroll
        for (int q = 0; q < 4; ++q) {
            float za = __uint_as_float(cells[key[i*8 + 2*q]]);
            float zb = __uint_as_float(cells[key[i*8 + 2*q + 1]]);
            li += loss_from(za, zb, (pack[i] >> (2 * q)) & 3);
        }
        if (i == SLOTS - 1) li *= (v6 ? 1.0f : 0.0f);
        acc += li;
    }

    // ---- wave + block reduction ----
    #pragma unroll
    for (int off2 = 32; off2 > 0; off2 >>= 1)
        acc += __shfl_down(acc, off2, 64);
    if (lane == 0) wsum[wid] = acc;
    __syncthreads();
    if (wid == 0) {
        float v = (lane < NWAVE) ? wsum[lane] : 0.0f;
        #pragma unroll
        for (int off2 = 4; off2 > 0; off2 >>= 1)
            v += __shfl_down(v, off2, 64);
        if (lane == 0) partials[j] = v;
    }
}

__global__ __launch_bounds__(256) void rdc_finalize(
        const float* __restrict__ partials, float* __restrict__ out, int n) {
    float acc = 0.0f;
    for (int k = threadIdx.x; k < n; k += 256)
        acc += partials[k];
    #pragma unroll
    for (int off = 32; off > 0; off >>= 1)
        acc += __shfl_down(acc, off, 64);
    __shared__ float wsum[4];
    int lane = threadIdx.x & 63;
    int wid  = threadIdx.x >> 6;
    if (lane == 0) wsum[wid] = acc;
    __syncthreads();
    if (wid == 0 && lane == 0)
        out[0] = (wsum[0] + wsum[1] + wsum[2] + wsum[3]) * INV_N;
}

extern "C" void kernel_launch(void* const* d_in, const int* in_sizes, int n_in,
                              void* d_out, int out_size, void* d_ws, size_t ws_size,
                              hipStream_t stream) {
    const float* depth = (const float*)d_in[0];
    const vint4* xA = (const vint4*)d_in[1];
    const vint4* yA = (const vint4*)d_in[2];
    const vint4* xB = (const vint4*)d_in[3];
    const vint4* yB = (const vint4*)d_in[4];
    const vint4* ord = (const vint4*)d_in[5];
    float* out = (float*)d_out;

    float* partials = (float*)d_ws;      // NBLK*4 = 2 KB, ws is plenty
    rdc_sweep<<<NBLK, THREADS, 0, stream>>>(depth, xA, yA, xB, yB, ord, partials);
    rdc_finalize<<<1, 256, 0, stream>>>(partials, out, NBLK);
}

// Round 7
// 271.514 us; speedup vs baseline: 1.2183x; 1.0698x over previous
//
#include <hip/hip_runtime.h>

// relative_depth_crit — R10: NCHUNK=4 + two-half-pass cells (min per-CU bytes).
// R9 post-mortem: staging rate is ~0.1 lines/cyc/CU across LDS-DMA, VGPR
// loads, all tile sizes, all barrier schemes => universal per-CU vmem ceiling
// ~10 B/cyc/CU (~48 outstanding lines x ~300cy). 256 CU x 10.2 B/cyc x 2.4GHz
// = 6.27 TB/s = the chip's "achievable HBM BW" — the cap is per-CU and
// applies to L2-resident streams too. Only lever: reduce per-CU bytes.
//   R9: 2 blocks/CU x (250KB idx + 1.31MB depth) = 3.11 MB/CU -> 127us model.
//   R10: NCHUNK=4, grid=256=1 block/CU: 500KB idx + 1.31MB depth = 1.81 MB/CU
//        -> ~75us floor.
// LDS can't hold 50000 endpoints (200KB) -> sweep the image in TWO half
// passes; cells holds only the current half's ~25000 endpoints (108KB).
// 104 keys/thread in registers; after pass-A readback each key reg is
// overwritten with its z bits (4-word bitmask remembers pass membership).

constexpr int B = 64;
constexpr int H = 512;
constexpr int W = 640;
constexpr int P = 100000;
constexpr int HWSZ = H * W;            // 327680 floats = 1.31 MB per batch
constexpr int N4B = P / 4;             // 25000 vec4 per batch
constexpr int NCHUNK = 4;              // blocks per batch
constexpr int C4 = N4B / NCHUNK;       // 6250 vec4 per block
constexpr int THREADS = 512;           // 8 waves
constexpr int NWAVE = 8;
constexpr int SLOTS = 13;              // ceil(6250/512) vec4 per thread
constexpr int NG = SLOTS * 8;          // 104 endpoints per thread
constexpr int NE = C4 * 8;             // 50000 endpoints per block
constexpr int TE = 4096;               // tile elems (16 KB); bin = key>>12
constexpr int T = HWSZ / TE;           // 80 tiles
constexpr int THALF = T / 2;           // 40 tiles per half
constexpr int CCAP = 27008;            // cells cap; n_half ~ 25000 +- 112 (1 sigma)
constexpr int NBLK = B * NCHUNK;       // 256 = one block per CU
constexpr int VTAIL = C4 - (SLOTS - 1) * THREADS;   // 106: slot-12 validity
constexpr float INV_N = 1.0f / (float)(B * P);
constexpr float MARGIN = 1.0f;

typedef int vint4 __attribute__((ext_vector_type(4)));
typedef float vfloat4 __attribute__((ext_vector_type(4)));

__device__ __forceinline__ float loss_from(float za, float zb, int od) {
    float zd = za - zb;
    float gt = (float)(od - 1);           // {-1, 0, 1}
    float mask = fabsf(gt);               // {0, 1}
    float t = fminf(gt * zd, MARGIN);
    float l_rank = __logf(1.0f + __expf(-t));
    float l_eq = fmaxf(zd * zd, MARGIN * MARGIN);
    return mask * l_rank + (1.0f - mask) * l_eq;
}

__global__ __launch_bounds__(THREADS) void rdc_sweep(
        const float* __restrict__ depth,
        const vint4* __restrict__ xA, const vint4* __restrict__ yA,
        const vint4* __restrict__ xB, const vint4* __restrict__ yB,
        const vint4* __restrict__ ord,
        float* __restrict__ partials) {
    __shared__ unsigned cells[CCAP];      // 108032 B: rel, then z bits
    __shared__ float tiles[2][TE];        //  32768 B, double-buffered
    __shared__ unsigned hist[NWAVE][T];   //   2560 B: per-wave histograms
    __shared__ unsigned cur[NWAVE][T];    //   2560 B: per-(wave,bin) cursors
    __shared__ unsigned startB[T + 1];    //    324 B: rebased bin starts
    __shared__ unsigned endA_s;           // entries in pass A (= start of bin 40)
    __shared__ float wsum[NWAVE];         // total ~146.3 KB -> 1 block/CU

    // XCD pinning: grid 256 = 8 XCDs x 32 slots. Batch b on XCD b&7; its 4
    // chunks co-resident on one XCD -> image L2-hot after first touch.
    const int j = blockIdx.x;
    const int x = j & 7;                  // XCD
    const int g = j >> 3;                 // 0..31 slot within XCD
    const int chunk = g & 3;
    const int b = ((g >> 2) << 3) + x;    // 0..63

    const int tid = threadIdx.x;
    const int lane = tid & 63;
    const int wid = tid >> 6;

    const float* dimg = depth + (size_t)b * HWSZ;

    // zero replica histograms: 8*80 = 640 words
    ((unsigned*)hist)[tid] = 0u;
    if (tid < NWAVE * T - THREADS) ((unsigned*)hist)[THREADS + tid] = 0u;

    // ---- index phase: 104 register-held keys + packed ordinals ----
    const int base4 = b * N4B + chunk * C4;
    const bool v12 = (tid < VTAIL);
    unsigned key[NG];                     // key -> cell idx -> z bits
    unsigned pack[SLOTS];
    #pragma unroll
    for (int i = 0; i < SLOTS; ++i) {
        int c = i * THREADS + tid;
        if (c > C4 - 1) c = C4 - 1;       // clamp tail (i==12, tid>=106)
        int idx = base4 + c;
        vint4 xa = __builtin_nontemporal_load(&xA[idx]);
        vint4 ya = __builtin_nontemporal_load(&yA[idx]);
        vint4 xb = __builtin_nontemporal_load(&xB[idx]);
        vint4 yb = __builtin_nontemporal_load(&yB[idx]);
        vint4 od = __builtin_nontemporal_load(&ord[idx]);
        key[i*8+0] = ya.x * W + xa.x;  key[i*8+1] = yb.x * W + xb.x;
        key[i*8+2] = ya.y * W + xa.y;  key[i*8+3] = yb.y * W + xb.y;
        key[i*8+4] = ya.z * W + xa.z;  key[i*8+5] = yb.z * W + xb.z;
        key[i*8+6] = ya.w * W + xa.w;  key[i*8+7] = yb.w * W + xb.w;
        pack[i] = (od.x & 3) | ((od.y & 3) << 2) | ((od.z & 3) << 4)
                | ((od.w & 3) << 6);
    }

    // depth prologue: tiles 0 and 1 -> regs (issued after the index burst so
    // index returns first; consumed only after placement A)
    vfloat4 t0a, t0b, r0, r1;
    {
        const vfloat4* s40 = (const vfloat4*)dimg;
        t0a = s40[tid];  t0b = s40[THREADS + tid];
        const vfloat4* s41 = (const vfloat4*)(dimg + TE);
        r0 = s41[tid];   r1 = s41[THREADS + tid];
    }
    __syncthreads();                      // hist zeroed visible

    // ---- histogram + pass-A membership bitmask ----
    unsigned mm[4] = {0u, 0u, 0u, 0u};
    #pragma unroll
    for (int k = 0; k < NG; ++k) {
        bool valid = (k < (SLOTS - 1) * 8) || v12;
        if (valid) {
            unsigned bin = key[k] >> 12;  // TE = 4096
            atomicAdd(&hist[wid][bin], 1u);
            if (bin < (unsigned)THALF) mm[k >> 5] |= (1u << (k & 31));
        }
    }
    __syncthreads();

    // ---- prefix scan (wave 0): lane l<40 owns bins 2l,2l+1; halves rebased ----
    if (wid == 0) {
        unsigned h0[NWAVE], h1[NWAVE];
        unsigned sum0 = 0, sum1 = 0;
        const int b0 = 2 * lane, b1 = 2 * lane + 1;
        if (lane < T / 2) {
            #pragma unroll
            for (int w = 0; w < NWAVE; ++w) h0[w] = hist[w][b0];
            #pragma unroll
            for (int w = 0; w < NWAVE; ++w) h1[w] = hist[w][b1];
            #pragma unroll
            for (int w = 0; w < NWAVE; ++w) { unsigned t_ = h0[w]; h0[w] = sum0; sum0 += t_; }
            #pragma unroll
            for (int w = 0; w < NWAVE; ++w) { unsigned t_ = h1[w]; h1[w] = sum1; sum1 += t_; }
        }
        unsigned pair = sum0 + sum1;      // 0 for lane >= 40
        unsigned inc = pair;
        #pragma unroll
        for (int d = 1; d < 64; d <<= 1) {
            unsigned n = __shfl_up(inc, d, 64);
            if (lane >= d) inc += n;
        }
        unsigned ex = inc - pair;         // exclusive over bin-pairs
        unsigned e40 = __shfl(ex, THALF / 2, 64);   // start of bin 40 = |pass A|
        if (lane == 0) endA_s = e40;
        if (lane < T / 2) {
            unsigned rb = (b0 >= THALF) ? e40 : 0u;
            unsigned s0 = ex - rb, s1 = ex + sum0 - rb;
            startB[b0] = s0;
            startB[b1] = s1;
            if (lane == T / 2 - 1) startB[T] = s1 + sum1;   // = NE - e40
            #pragma unroll
            for (int w = 0; w < NWAVE; ++w) {
                cur[w][b0] = s0 + h0[w];
                cur[w][b1] = s1 + h1[w];
            }
        }
    }
    __syncthreads();

    // ---- placement A: endpoints with bin < 40 ----
    #pragma unroll
    for (int k = 0; k < NG; ++k) {
        if ((mm[k >> 5] >> (k & 31)) & 1u) {
            unsigned kk = key[k];
            unsigned bin = kk >> 12;
            unsigned pos = atomicAdd(&cur[wid][bin], 1u);
            cells[pos] = kk & (unsigned)(TE - 1);
            key[k] = pos;                 // key -> cell index
        }
    }
    // write tile 0 from regs (loads long landed)
    {
        vfloat4* d4 = (vfloat4*)&tiles[0][0];
        d4[tid] = t0a;
        d4[THREADS + tid] = t0b;
    }
    __syncthreads();                      // placement A + tile 0 visible

    // ---- two-half reg-staged sweep; interlude at the half boundary ----
    // invariant at top of iter t: buf[t&1] holds tile t; regs hold tile t+1.
    #pragma unroll 1
    for (int t = 0; t < T; ++t) {
        if (t == THALF) {
            // readback A: pull pass-A z into key regs, freeing cells
            #pragma unroll
            for (int k = 0; k < NG; ++k) {
                if ((mm[k >> 5] >> (k & 31)) & 1u)
                    key[k] = cells[key[k]];
            }
            __syncthreads();
            // placement B: endpoints with bin >= 40 (key still intact)
            #pragma unroll
            for (int k = 0; k < NG; ++k) {
                bool valid = (k < (SLOTS - 1) * 8) || v12;
                if (valid && !((mm[k >> 5] >> (k & 31)) & 1u)) {
                    unsigned kk = key[k];
                    unsigned bin = kk >> 12;
                    unsigned pos = atomicAdd(&cur[wid][bin], 1u);
                    cells[pos] = kk & (unsigned)(TE - 1);
                    key[k] = pos;
                }
            }
            __syncthreads();
        }
        if (t + 1 < T) {
            vfloat4* d4 = (vfloat4*)&tiles[(t + 1) & 1][0];
            d4[tid] = r0;                 // implicit wait on tile-(t+1) loads
            d4[THREADS + tid] = r1;
        }
        if (t + 2 < T) {
            const vfloat4* s4 = (const vfloat4*)(dimg + (size_t)(t + 2) * TE);
            r0 = s4[tid];
            r1 = s4[THREADS + tid];
        }
        const float* tb = &tiles[t & 1][0];
        unsigned s = startB[t];
        unsigned e = (t == THALF - 1) ? endA_s : startB[t + 1];
        for (unsigned u = s + tid; u < e; u += THREADS) {
            unsigned rel = cells[u];
            cells[u] = __float_as_uint(tb[rel]);
        }
        __syncthreads();
    }

    // ---- readback B + loss ----
    #pragma unroll
    for (int k = 0; k < NG; ++k) {
        bool valid = (k < (SLOTS - 1) * 8) || v12;
        if (valid && !((mm[k >> 5] >> (k & 31)) & 1u))
            key[k] = cells[key[k]];
    }
    float acc = 0.0f;
    #pragma unroll
    for (int i = 0; i < SLOTS; ++i) {
        float li = 0.0f;
        #pragma unroll
        for (int q = 0; q < 4; ++q) {
            float za = __uint_as_float(key[i*8 + 2*q]);
            float zb = __uint_as_float(key[i*8 + 2*q + 1]);
            li += loss_from(za, zb, (int)((pack[i] >> (2 * q)) & 3u));
        }
        if (i == SLOTS - 1) li *= (v12 ? 1.0f : 0.0f);
        acc += li;
    }

    // ---- wave + block reduction ----
    #pragma unroll
    for (int off2 = 32; off2 > 0; off2 >>= 1)
        acc += __shfl_down(acc, off2, 64);
    if (lane == 0) wsum[wid] = acc;
    __syncthreads();
    if (wid == 0) {
        float v = (lane < NWAVE) ? wsum[lane] : 0.0f;
        #pragma unroll
        for (int off2 = 4; off2 > 0; off2 >>= 1)
            v += __shfl_down(v, off2, 64);
        if (lane == 0) partials[j] = v;
    }
}

__global__ __launch_bounds__(256) void rdc_finalize(
        const float* __restrict__ partials, float* __restrict__ out, int n) {
    float acc = 0.0f;
    for (int k = threadIdx.x; k < n; k += 256)
        acc += partials[k];
    #pragma unroll
    for (int off = 32; off > 0; off >>= 1)
        acc += __shfl_down(acc, off, 64);
    __shared__ float wsum[4];
    int lane = threadIdx.x & 63;
    int wid  = threadIdx.x >> 6;
    if (lane == 0) wsum[wid] = acc;
    __syncthreads();
    if (wid == 0 && lane == 0)
        out[0] = (wsum[0] + wsum[1] + wsum[2] + wsum[3]) * INV_N;
}

extern "C" void kernel_launch(void* const* d_in, const int* in_sizes, int n_in,
                              void* d_out, int out_size, void* d_ws, size_t ws_size,
                              hipStream_t stream) {
    const float* depth = (const float*)d_in[0];
    const vint4* xA = (const vint4*)d_in[1];
    const vint4* yA = (const vint4*)d_in[2];
    const vint4* xB = (const vint4*)d_in[3];
    const vint4* yB = (const vint4*)d_in[4];
    const vint4* ord = (const vint4*)d_in[5];
    float* out = (float*)d_out;

    float* partials = (float*)d_ws;      // NBLK*4 = 1 KB, ws is plenty
    rdc_sweep<<<NBLK, THREADS, 0, stream>>>(depth, xA, yA, xB, yB, ord, partials);
    rdc_finalize<<<1, 256, 0, stream>>>(partials, out, NBLK);
}